// Round 1
// baseline (363.042 us; speedup 1.0000x reference)
//
#include <hip/hip_runtime.h>
#include <hip/hip_bf16.h>

// Problem constants
#define MQ 8        // codebooks
#define KQ 4096     // codes per codebook
#define DG 64       // dims per group (D/M)
#define NN 32       // batch
#define HW 4096     // 64*64 spatial
#define DD 512      // output channels

// ---------------------------------------------------------------------------
// Kernel 1: v[m,k,c] = sum_d codebook[m,k,d] * wv[m,c,d]
// grid (64, 8): blockIdx.x = k-tile of 64 rows, blockIdx.y = m
// wv staged transposed in LDS (pad +1 to break stride-64 bank conflicts),
// codebook tile staged in LDS (broadcast reads, no conflict).
// ---------------------------------------------------------------------------
__global__ __launch_bounds__(256) void compute_v_kernel(
    const float* __restrict__ codebook,
    const float* __restrict__ wv,
    float* __restrict__ v) {
  __shared__ float wv_t[DG][DG + 1];   // [d][c], padded
  __shared__ float cb[64][DG];         // [k_local][d]

  const int m = blockIdx.y;
  const int k0 = blockIdx.x * 64;
  const int tid = threadIdx.x;

  const float* wvm = wv + (size_t)m * DG * DG;          // wv[m][c][d]
  for (int i = tid; i < DG * DG; i += 256) {
    int c = i >> 6, d = i & 63;
    wv_t[d][c] = wvm[i];
  }
  const float* cbm = codebook + ((size_t)m * KQ + k0) * DG;
  for (int i = tid; i < 64 * DG; i += 256) {
    cb[i >> 6][i & 63] = cbm[i];
  }
  __syncthreads();

  const int c = tid & 63;     // output column
  const int kq = tid >> 6;    // 0..3, each owns 16 k rows

  float acc[16];
#pragma unroll
  for (int kl = 0; kl < 16; ++kl) acc[kl] = 0.f;

  for (int d = 0; d < DG; ++d) {
    float w = wv_t[d][c];     // conflict-free (stride 65)
#pragma unroll
    for (int kl = 0; kl < 16; ++kl) {
      acc[kl] += cb[kq * 16 + kl][d] * w;   // broadcast read
    }
  }

  float* vout = v + ((size_t)m * KQ + k0) * DG;
#pragma unroll
  for (int kl = 0; kl < 16; ++kl) {
    vout[(size_t)(kq * 16 + kl) * DG + c] = acc[kl];   // coalesced
  }
}

// ---------------------------------------------------------------------------
// Kernel 2: out[n, m*64+c, hw] = v[m, codes[n,hw,m], c]
// 1024 blocks x 256 threads. Each thread owns 4 consecutive hw for one
// (n, m, hw-chunk); reads its 4 codes once, then for each group of 4 c's
// loads 4x float4 rows of v and writes 4 float4 coalesced stores.
// m = blockIdx % 8 -> same-m blocks land on the same XCD (round-robin),
// so the 1 MB v[m] slab stays hot in that XCD's L2.
// ---------------------------------------------------------------------------
__global__ __launch_bounds__(256) void gather_kernel(
    const int* __restrict__ codes,
    const float* __restrict__ v,
    float* __restrict__ out) {
  const int b = blockIdx.x;
  const int m = b & 7;
  const int t = b >> 3;
  const int n = t & 31;
  const int chunk = t >> 5;                 // 0..3
  const int hw = chunk * 1024 + threadIdx.x * 4;

  const int cbase = (n * HW + hw) * MQ + m; // codes[n, hw, m]
  const int r0 = codes[cbase];
  const int r1 = codes[cbase + MQ];
  const int r2 = codes[cbase + 2 * MQ];
  const int r3 = codes[cbase + 3 * MQ];

  const float* vm = v + (size_t)m * KQ * DG;
  const float4* p0 = (const float4*)(vm + (size_t)r0 * DG);
  const float4* p1 = (const float4*)(vm + (size_t)r1 * DG);
  const float4* p2 = (const float4*)(vm + (size_t)r2 * DG);
  const float4* p3 = (const float4*)(vm + (size_t)r3 * DG);

  float* outbase = out + ((size_t)n * DD + m * DG) * HW + hw;

#pragma unroll 4
  for (int cg = 0; cg < 16; ++cg) {
    float4 a0 = p0[cg];
    float4 a1 = p1[cg];
    float4 a2 = p2[cg];
    float4 a3 = p3[cg];
    float4 w;
    w.x = a0.x; w.y = a1.x; w.z = a2.x; w.w = a3.x;
    *(float4*)(outbase + (size_t)(cg * 4 + 0) * HW) = w;
    w.x = a0.y; w.y = a1.y; w.z = a2.y; w.w = a3.y;
    *(float4*)(outbase + (size_t)(cg * 4 + 1) * HW) = w;
    w.x = a0.z; w.y = a1.z; w.z = a2.z; w.w = a3.z;
    *(float4*)(outbase + (size_t)(cg * 4 + 2) * HW) = w;
    w.x = a0.w; w.y = a1.w; w.z = a2.w; w.w = a3.w;
    *(float4*)(outbase + (size_t)(cg * 4 + 3) * HW) = w;
  }
}

extern "C" void kernel_launch(void* const* d_in, const int* in_sizes, int n_in,
                              void* d_out, int out_size, void* d_ws, size_t ws_size,
                              hipStream_t stream) {
  const int* codes = (const int*)d_in[0];        // (32,64,64,8) int32
  const float* codebook = (const float*)d_in[1]; // (8,4096,64) f32
  const float* wv = (const float*)d_in[2];       // (8,64,64) f32
  float* out = (float*)d_out;                    // (32,512,64,64) f32
  float* v = (float*)d_ws;                       // 8*4096*64 f32 = 8 MB scratch

  compute_v_kernel<<<dim3(64, 8), 256, 0, stream>>>(codebook, wv, v);
  gather_kernel<<<1024, 256, 0, stream>>>(codes, v, out);
}

// Round 2
// 316.779 us; speedup vs baseline: 1.1460x; 1.1460x over previous
//
#include <hip/hip_runtime.h>
#include <hip/hip_bf16.h>

// Problem constants
#define MQ 8        // codebooks
#define KQ 4096     // codes per codebook
#define DG 64       // dims per group (D/M)
#define NN 32       // batch
#define HW 4096     // 64*64 spatial
#define DD 512      // output channels
#define THW 128     // hw tile per gather block

// ---------------------------------------------------------------------------
// Kernel 1: v[m,k,c] = sum_d codebook[m,k,d] * wv[m,c,d]
// grid (64, 8). wv transposed in LDS (stride 65, conflict-free), codebook
// tile in LDS read as float4 broadcasts (same-address -> no conflict).
// ---------------------------------------------------------------------------
__global__ __launch_bounds__(256) void compute_v_kernel(
    const float* __restrict__ codebook,
    const float* __restrict__ wv,
    float* __restrict__ v) {
  __shared__ float wv_t[DG][DG + 1];   // [d][c]
  __shared__ float cb[64][DG];         // [k_local][d], rows 16B-aligned

  const int m = blockIdx.y;
  const int k0 = blockIdx.x * 64;
  const int tid = threadIdx.x;

  // stage wv[m][c][d] transposed -> wv_t[d][c]
  const float4* wvm4 = (const float4*)(wv + (size_t)m * DG * DG);
  for (int i = tid; i < DG * DG / 4; i += 256) {
    int c = i >> 4, d4 = (i & 15) * 4;
    float4 val = wvm4[i];
    wv_t[d4 + 0][c] = val.x;
    wv_t[d4 + 1][c] = val.y;
    wv_t[d4 + 2][c] = val.z;
    wv_t[d4 + 3][c] = val.w;
  }
  // stage codebook tile (contiguous float4)
  const float4* cbm4 = (const float4*)(codebook + ((size_t)m * KQ + k0) * DG);
  float4* cb4 = (float4*)&cb[0][0];
  for (int i = tid; i < 64 * DG / 4; i += 256) cb4[i] = cbm4[i];
  __syncthreads();

  const int c = tid & 63;     // output column
  const int kq = tid >> 6;    // 0..3, each owns 16 k rows

  float acc[16];
#pragma unroll
  for (int kl = 0; kl < 16; ++kl) acc[kl] = 0.f;

  for (int d4 = 0; d4 < DG; d4 += 4) {
    float w0 = wv_t[d4 + 0][c];
    float w1 = wv_t[d4 + 1][c];
    float w2 = wv_t[d4 + 2][c];
    float w3 = wv_t[d4 + 3][c];
#pragma unroll
    for (int kl = 0; kl < 16; ++kl) {
      float4 cbv = *(const float4*)&cb[kq * 16 + kl][d4];  // broadcast b128
      acc[kl] += cbv.x * w0 + cbv.y * w1 + cbv.z * w2 + cbv.w * w3;
    }
  }

  float* vout = v + ((size_t)m * KQ + k0) * DG;
#pragma unroll
  for (int kl = 0; kl < 16; ++kl) {
    vout[(size_t)(kq * 16 + kl) * DG + c] = acc[kl];   // coalesced
  }
}

// ---------------------------------------------------------------------------
// Kernel 2: out[n, m*64+c, hw] = v[m, codes[n,hw,m], c]
// Block = (n, m, 128-hw tile), 256 threads, grid 8192.
// Phase 1: stage 128 codes in LDS.
// Phase 2: one v-row per wave-iteration, fully coalesced 256 B reads,
//          32 independent rows per wave -> deep load pipeline.
//          LDS tile[j][c] stride 65: write banks (j+l)%32 -> conflict-free.
// Phase 3: read tile[j][c] (banks (l+c)%32, conflict-free), nontemporal
//          256 B-contiguous stores (don't thrash L2; keep v slab hot).
// m = blockIdx & 7: round-robin XCD heuristic pins v[m] (1 MB) per-XCD L2.
// ---------------------------------------------------------------------------
__global__ __launch_bounds__(256) void gather_kernel(
    const int* __restrict__ codes,
    const float* __restrict__ v,
    float* __restrict__ out) {
  __shared__ int scode[THW];
  __shared__ float tile[THW][DG + 1];   // [hw_local][c], stride 65

  const int b = blockIdx.x;
  const int m = b & 7;
  const int t = b >> 3;
  const int n = t & 31;
  const int tileidx = t >> 5;           // 0..31
  const int hw0 = tileidx * THW;

  const int tid = threadIdx.x;
  const int w = tid >> 6;               // wave 0..3
  const int l = tid & 63;               // lane

  // Phase 1: codes[n, hw0+t, m]
  if (tid < THW) {
    scode[tid] = codes[((size_t)n * HW + hw0 + tid) * MQ + m];
  }
  __syncthreads();

  // Phase 2: gather rows, coalesced
  const float* vm = v + (size_t)m * KQ * DG;
#pragma unroll 8
  for (int jj = 0; jj < 32; ++jj) {
    int j = w * 32 + jj;
    int r = scode[j];                   // wave-uniform broadcast
    tile[j][l] = vm[(size_t)r * DG + l];
  }
  __syncthreads();

  // Phase 3: transposed write-out
  float* outb = out + ((size_t)n * DD + (size_t)m * DG) * HW + hw0;
#pragma unroll 4
  for (int u = 0; u < 16; ++u) {
    int up = w * 16 + u;
    int c = up >> 1;                    // 0..7 within wave's range... c = up>>1 spans 0..31? 
    int half = up & 1;
    // up ranges 0..63 across waves: c = up>>1 in 0..31 -> need 64 c's.
    // Handle 2 c's per iteration instead:
    int j = half * 64 + l;
    float val0 = tile[j][c];
    float val1 = tile[j][c + 32];
    __builtin_nontemporal_store(val0, outb + (size_t)c * HW + j);
    __builtin_nontemporal_store(val1, outb + (size_t)(c + 32) * HW + j);
  }
}

extern "C" void kernel_launch(void* const* d_in, const int* in_sizes, int n_in,
                              void* d_out, int out_size, void* d_ws, size_t ws_size,
                              hipStream_t stream) {
  const int* codes = (const int*)d_in[0];        // (32,64,64,8) int32
  const float* codebook = (const float*)d_in[1]; // (8,4096,64) f32
  const float* wv = (const float*)d_in[2];       // (8,64,64) f32
  float* out = (float*)d_out;                    // (32,512,64,64) f32
  float* v = (float*)d_ws;                       // 8*4096*64 f32 = 8 MB scratch

  compute_v_kernel<<<dim3(64, 8), 256, 0, stream>>>(codebook, wv, v);
  gather_kernel<<<NN * MQ * (HW / THW), 256, 0, stream>>>(codes, v, out);
}

// Round 4
// 301.709 us; speedup vs baseline: 1.2033x; 1.0499x over previous
//
#include <hip/hip_runtime.h>
#include <hip/hip_bf16.h>

// Problem constants
#define MQ 8        // codebooks
#define KQ 4096     // codes per codebook
#define DG 64       // dims per group (D/M)
#define NN 32       // batch
#define HW 4096     // 64*64 spatial
#define DD 512      // output channels
#define THW 256     // hw tile per gather block (1 KB contiguous run per c)
#define TS 33       // tile row stride (odd -> conflict-free column reads)

// ---------------------------------------------------------------------------
// Kernel 1: v[m,k,c] = sum_d codebook[m,k,d] * wv[m,c,d]   (round-2, passed)
// ---------------------------------------------------------------------------
__global__ __launch_bounds__(256) void compute_v_kernel(
    const float* __restrict__ codebook,
    const float* __restrict__ wv,
    float* __restrict__ v) {
  __shared__ float wv_t[DG][DG + 1];   // [d][c]
  __shared__ float cb[64][DG];         // [k_local][d]

  const int m = blockIdx.y;
  const int k0 = blockIdx.x * 64;
  const int tid = threadIdx.x;

  const float4* wvm4 = (const float4*)(wv + (size_t)m * DG * DG);
  for (int i = tid; i < DG * DG / 4; i += 256) {
    int c = i >> 4, d4 = (i & 15) * 4;
    float4 val = wvm4[i];
    wv_t[d4 + 0][c] = val.x;
    wv_t[d4 + 1][c] = val.y;
    wv_t[d4 + 2][c] = val.z;
    wv_t[d4 + 3][c] = val.w;
  }
  const float4* cbm4 = (const float4*)(codebook + ((size_t)m * KQ + k0) * DG);
  float4* cb4 = (float4*)&cb[0][0];
  for (int i = tid; i < 64 * DG / 4; i += 256) cb4[i] = cbm4[i];
  __syncthreads();

  const int c = tid & 63;
  const int kq = tid >> 6;

  float acc[16];
#pragma unroll
  for (int kl = 0; kl < 16; ++kl) acc[kl] = 0.f;

  for (int d4 = 0; d4 < DG; d4 += 4) {
    float w0 = wv_t[d4 + 0][c];
    float w1 = wv_t[d4 + 1][c];
    float w2 = wv_t[d4 + 2][c];
    float w3 = wv_t[d4 + 3][c];
#pragma unroll
    for (int kl = 0; kl < 16; ++kl) {
      float4 cbv = *(const float4*)&cb[kq * 16 + kl][d4];  // broadcast b128
      acc[kl] += cbv.x * w0 + cbv.y * w1 + cbv.z * w2 + cbv.w * w3;
    }
  }

  float* vout = v + ((size_t)m * KQ + k0) * DG;
#pragma unroll
  for (int kl = 0; kl < 16; ++kl) {
    vout[(size_t)(kq * 16 + kl) * DG + c] = acc[kl];
  }
}

// ---------------------------------------------------------------------------
// Kernel 2: out[n, m*64+c, hw] = v[m, codes[n,hw,m], c]
// Block = (n, m, 256-hw tile), 256 threads, grid 4096 (= 32n x 8m x 16 tiles).
// Processed in two c-halves of 32 so LDS stays at 34.8 KB -> 4 blocks/CU:
//   load half:  each iter, 8 lanes share a v-row; lane loads float4 of 4 c's
//               (coalesced 128 B/row, 8 rows per wave-instr, MLP=8),
//               scatters 4 scalar ds_writes into tile[j][cc] (TS=33 -> ~2-way).
//   store half: scalar reads tile[j][cc] (bank (j+cc)%32, 2-way = free),
//               nontemporal dword stores; per c the 4 q-instrs are
//               back-to-back -> 1 KB contiguous HBM run (vs 512 B in round 2).
// m = blockIdx & 7: round-robin XCD heuristic keeps v[m] (1 MB) in one L2.
// ---------------------------------------------------------------------------
__global__ __launch_bounds__(256) void gather_kernel(
    const int* __restrict__ codes,
    const float* __restrict__ v,
    float* __restrict__ out) {
  __shared__ int scode[THW];
  __shared__ float tile[THW][TS];       // [hw_local][c_half], stride 33

  const int b = blockIdx.x;
  const int m = b & 7;
  const int t = b >> 3;
  const int n = t & 31;
  const int hw0 = (t >> 5) * THW;       // t>>5 in 0..15

  const int tid = threadIdx.x;
  const int w = tid >> 6;               // wave 0..3
  const int l = tid & 63;               // lane

  scode[tid] = codes[((size_t)n * HW + hw0 + tid) * MQ + m];
  __syncthreads();

  const float* vm = v + (size_t)m * KQ * DG;
  float* outb = out + ((size_t)n * DD + (size_t)m * DG) * HW + hw0;

#pragma unroll
  for (int ch = 0; ch < 2; ++ch) {
    // ---- load half: 2048 float4 loads, 8 per thread ----
#pragma unroll
    for (int iter = 0; iter < 8; ++iter) {
      int i = iter * 256 + tid;         // 0..2047
      int j = i >> 3;                   // row 0..255
      int bq = i & 7;                   // which 16B chunk of the half
      int r = scode[j];
      float4 val = *(const float4*)(vm + (size_t)r * DG + ch * 32 + bq * 4);
      tile[j][bq * 4 + 0] = val.x;
      tile[j][bq * 4 + 1] = val.y;
      tile[j][bq * 4 + 2] = val.z;
      tile[j][bq * 4 + 3] = val.w;
    }
    __syncthreads();

    // ---- store half: 32 c's, 1 KB contiguous per c ----
#pragma unroll
    for (int u = 0; u < 8; ++u) {
      int cc = w * 8 + u;               // 0..31 within half
      int c = ch * 32 + cc;
#pragma unroll
      for (int q = 0; q < 4; ++q) {
        int j = q * 64 + l;
        __builtin_nontemporal_store(tile[j][cc],
                                    outb + (size_t)c * HW + j);
      }
    }
    __syncthreads();                    // tile reused by next half
  }
}

extern "C" void kernel_launch(void* const* d_in, const int* in_sizes, int n_in,
                              void* d_out, int out_size, void* d_ws, size_t ws_size,
                              hipStream_t stream) {
  const int* codes = (const int*)d_in[0];        // (32,64,64,8) int32
  const float* codebook = (const float*)d_in[1]; // (8,4096,64) f32
  const float* wv = (const float*)d_in[2];       // (8,64,64) f32
  float* out = (float*)d_out;                    // (32,512,64,64) f32
  float* v = (float*)d_ws;                       // 8*4096*64 f32 = 8 MB scratch

  compute_v_kernel<<<dim3(64, 8), 256, 0, stream>>>(codebook, wv, v);
  gather_kernel<<<NN * MQ * (HW / THW), 256, 0, stream>>>(codes, v, out);
}